// Round 1
// baseline (188.955 us; speedup 1.0000x reference)
//
#include <hip/hip_runtime.h>

// PointProjection: B=32, N=4096 points, 4 feature pyramids (64,32,16,8),
// C = (64,128,256,512), output (B,N,960) + hc (B,N,1) + wc (B,N,1).
//
// Key simplification (faithful to the reference): with xi = trunc(x) = floor(x)
// = x1 (x < s always), the weights w12/w21/w22 are identically 0 and
// w11 = (x2-x1)*(y2-y1) in {0,1}. Output channel = w11 ? feat[b,c,y1,x1] : 0.

#define BB 32
#define NN 4096
#define NPTS (BB * NN)              // 131072 points
#define FEAT_ELEMS (NPTS * 960)     // 125829120 f32 of pixel_feature

// ---------------- Phase 1: projection + per-point gather meta ----------------
__global__ void __launch_bounds__(256)
proj_phase1(const float* __restrict__ points,
            const float* __restrict__ proM,
            float* __restrict__ out_hc,
            float* __restrict__ out_wc,
            int4* __restrict__ meta)
{
    int pt = blockIdx.x * blockDim.x + threadIdx.x;
    if (pt >= NPTS) return;
    int b = pt >> 12;                       // N = 4096
    const float* p = points + (size_t)pt * 3;
    float px = p[0], py = p[1], pz = p[2];
    const float* M = proM + b * 12;
    // einsum order matches numpy: sum_j M[i][j] * p4[j]
    float a0 = M[0] * px + M[1] * py + M[2]  * pz + M[3];
    float a1 = M[4] * px + M[5] * py + M[6]  * pz + M[7];
    float a2 = M[8] * px + M[9] * py + M[10] * pz + M[11];
    float wcv = fminf(fmaxf(a0 / a2, 0.0f), 127.0f);
    float hcv = fminf(fmaxf(a1 / a2, 0.0f), 127.0f);
    out_hc[pt] = hcv;
    out_wc[pt] = wcv;

    int res[4];
    const int sizes[4] = {64, 32, 16, 8};
#pragma unroll
    for (int k = 0; k < 4; ++k) {
        int s = sizes[k];
        float sc = (float)s * (1.0f / 128.0f);   // exact pow2 scaling == x/scale
        float x = wcv * sc;
        float y = hcv * sc;
        int x1 = (int)x;                          // trunc == floor (x >= 0)
        int y1 = (int)y;
        int x2 = min((int)ceilf(x), s - 1);
        int y2 = min((int)ceilf(y), s - 1);
        int w  = (x2 - x1) * (y2 - y1);           // 0 or 1
        res[k] = w ? (y1 * s + x1) : -1;
    }
    meta[pt] = make_int4(res[0], res[1], res[2], res[3]);
}

// ---------------- Phase 2: masked gather, float4 per thread ----------------
__global__ void __launch_bounds__(256)
proj_phase2(const float* __restrict__ f0,
            const float* __restrict__ f1,
            const float* __restrict__ f2,
            const float* __restrict__ f3,
            const int4* __restrict__ meta,
            float4* __restrict__ outf)
{
    int i = blockIdx.x * blockDim.x + threadIdx.x;   // float4 index < 31457280
    int pt = i / 240;                                // 240 float4 per point
    int r  = i - pt * 240;
    int c4 = r << 2;                                 // channel of .x
    int b  = pt >> 12;
    int4 m = meta[pt];

    const float* src;
    int mm, ss2, c0;
    if (c4 < 64)       { src = f0 + (size_t)b * (64  * 4096); mm = m.x; ss2 = 64 * 64; c0 = c4;       }
    else if (c4 < 192) { src = f1 + (size_t)b * (128 * 1024); mm = m.y; ss2 = 32 * 32; c0 = c4 - 64;  }
    else if (c4 < 448) { src = f2 + (size_t)b * (256 * 256);  mm = m.z; ss2 = 16 * 16; c0 = c4 - 192; }
    else               { src = f3 + (size_t)b * (512 * 64);   mm = m.w; ss2 = 8 * 8;   c0 = c4 - 448; }

    float4 v;
    if (mm < 0) {
        v = make_float4(0.f, 0.f, 0.f, 0.f);
    } else {
        const float* g = src + (size_t)c0 * ss2 + mm;
        v.x = g[0];
        v.y = g[ss2];
        v.z = g[2 * ss2];
        v.w = g[3 * ss2];
    }
    outf[i] = v;
}

extern "C" void kernel_launch(void* const* d_in, const int* in_sizes, int n_in,
                              void* d_out, int out_size, void* d_ws, size_t ws_size,
                              hipStream_t stream)
{
    const float* f0     = (const float*)d_in[0];
    const float* f1     = (const float*)d_in[1];
    const float* f2     = (const float*)d_in[2];
    const float* f3     = (const float*)d_in[3];
    const float* points = (const float*)d_in[4];
    const float* proM   = (const float*)d_in[5];

    float* out      = (float*)d_out;
    float* out_hc   = out + (size_t)FEAT_ELEMS;
    float* out_wc   = out_hc + NPTS;
    int4*  meta     = (int4*)d_ws;                 // 131072 * 16 B = 2 MiB

    // Phase 1: one thread per point
    {
        dim3 grid((NPTS + 255) / 256), block(256);
        proj_phase1<<<grid, block, 0, stream>>>(points, proM, out_hc, out_wc, meta);
    }
    // Phase 2: one thread per output float4
    {
        int total4 = FEAT_ELEMS / 4;               // 31457280
        dim3 grid(total4 / 256), block(256);       // divides exactly
        proj_phase2<<<grid, block, 0, stream>>>(f0, f1, f2, f3, meta, (float4*)out);
    }
}

// Round 3
// 103.402 us; speedup vs baseline: 1.8274x; 1.8274x over previous
//
#include <hip/hip_runtime.h>

// PointProjection: B=32, N=4096, pyramids s=(64,32,16,8), C=(64,128,256,512).
// Output (B,N,960) + hc (B,N,1) + wc (B,N,1).
//
// Reference degenerates: xi==x1 always, so w12=w21=w22=0 and w11 in {0,1}.
// Each point is either a full 960-ch gather of pixel (y1,x1) or all zeros.
//
// R3: same as R2 (transpose features (C,s,s)->(s*s,C) into d_ws; contiguous
// row gather; non-temporal output stores) but with a native ext_vector float4
// so __builtin_nontemporal_store compiles.

#define BB 32
#define NN 4096
#define NPTS (BB * NN)              // 131072 points
#define FEAT_ELEMS (NPTS * 960)     // 125829120 f32 of pixel_feature

typedef float v4f __attribute__((ext_vector_type(4)));

// ---------------- Transpose (b, C, P) -> (b, P, C), 32x32 LDS tiles --------
__global__ void __launch_bounds__(256)
transpose_k(const float* __restrict__ in, float* __restrict__ out, int C, int P)
{
    __shared__ float t[32][33];
    int b = blockIdx.z;
    int p0 = blockIdx.x << 5, c0 = blockIdx.y << 5;
    const float* ib = in + (size_t)b * C * P;
    float* ob = out + (size_t)b * C * P;
    int tx = threadIdx.x, ty = threadIdx.y;   // 32 x 8
#pragma unroll
    for (int i = 0; i < 32; i += 8)
        t[ty + i][tx] = ib[(size_t)(c0 + ty + i) * P + p0 + tx];
    __syncthreads();
#pragma unroll
    for (int i = 0; i < 32; i += 8)
        ob[(size_t)(p0 + ty + i) * C + c0 + tx] = t[tx][ty + i];
}

// ---------------- Phase 1: projection + per-point gather meta ----------------
__global__ void __launch_bounds__(256)
proj_phase1(const float* __restrict__ points,
            const float* __restrict__ proM,
            float* __restrict__ out_hc,
            float* __restrict__ out_wc,
            int4* __restrict__ meta)
{
    int pt = blockIdx.x * blockDim.x + threadIdx.x;
    if (pt >= NPTS) return;
    int b = pt >> 12;
    const float* p = points + (size_t)pt * 3;
    float px = p[0], py = p[1], pz = p[2];
    const float* M = proM + b * 12;
    float a0 = M[0] * px + M[1] * py + M[2]  * pz + M[3];
    float a1 = M[4] * px + M[5] * py + M[6]  * pz + M[7];
    float a2 = M[8] * px + M[9] * py + M[10] * pz + M[11];
    float wcv = fminf(fmaxf(a0 / a2, 0.0f), 127.0f);
    float hcv = fminf(fmaxf(a1 / a2, 0.0f), 127.0f);
    out_hc[pt] = hcv;
    out_wc[pt] = wcv;

    int res[4];
    const int sizes[4] = {64, 32, 16, 8};
#pragma unroll
    for (int k = 0; k < 4; ++k) {
        int s = sizes[k];
        float sc = (float)s * (1.0f / 128.0f);
        float x = wcv * sc;
        float y = hcv * sc;
        int x1 = (int)x;
        int y1 = (int)y;
        int x2 = min((int)ceilf(x), s - 1);
        int y2 = min((int)ceilf(y), s - 1);
        int w  = (x2 - x1) * (y2 - y1);           // 0 or 1
        res[k] = w ? (y1 * s + x1) : -1;
    }
    meta[pt] = make_int4(res[0], res[1], res[2], res[3]);
}

// ---------------- Phase 2: contiguous row gather, float4 per thread --------
__global__ void __launch_bounds__(256)
proj_phase2(const v4f* __restrict__ T0,   // (b, 4096, 64)
            const v4f* __restrict__ T1,   // (b, 1024, 128)
            const v4f* __restrict__ T2,   // (b, 256, 256)
            const v4f* __restrict__ T3,   // (b, 64, 512)
            const int4* __restrict__ meta,
            v4f* __restrict__ outf)
{
    int i = blockIdx.x * blockDim.x + threadIdx.x;   // < 31457280
    int pt = i / 240;                                // 240 float4 per point
    int r  = i - pt * 240;
    int b  = pt >> 12;
    int4 m = meta[pt];

    v4f v = (v4f)(0.f, 0.f, 0.f, 0.f);
    if (r < 16) {
        if (m.x >= 0) v = T0[((size_t)b * 4096 + m.x) * 16 + r];
    } else if (r < 48) {
        if (m.y >= 0) v = T1[((size_t)b * 1024 + m.y) * 32 + (r - 16)];
    } else if (r < 112) {
        if (m.z >= 0) v = T2[((size_t)b * 256 + m.z) * 64 + (r - 48)];
    } else {
        if (m.w >= 0) v = T3[((size_t)b * 64 + m.w) * 128 + (r - 112)];
    }
    __builtin_nontemporal_store(v, &outf[i]);
}

extern "C" void kernel_launch(void* const* d_in, const int* in_sizes, int n_in,
                              void* d_out, int out_size, void* d_ws, size_t ws_size,
                              hipStream_t stream)
{
    const float* f0     = (const float*)d_in[0];
    const float* f1     = (const float*)d_in[1];
    const float* f2     = (const float*)d_in[2];
    const float* f3     = (const float*)d_in[3];
    const float* points = (const float*)d_in[4];
    const float* proM   = (const float*)d_in[5];

    float* out      = (float*)d_out;
    float* out_hc   = out + (size_t)FEAT_ELEMS;
    float* out_wc   = out_hc + NPTS;

    // Workspace layout (floats): T0 | T1 | T2 | T3 | meta
    float* T0 = (float*)d_ws;                          // 32*4096*64  = 8388608
    float* T1 = T0 + (size_t)32 * 4096 * 64;           // 32*1024*128 = 4194304
    float* T2 = T1 + (size_t)32 * 1024 * 128;          // 32*256*256  = 2097152
    float* T3 = T2 + (size_t)32 * 256 * 256;           // 32*64*512   = 1048576
    int4*  meta = (int4*)(T3 + (size_t)32 * 64 * 512); // 2 MiB

    dim3 tb(32, 8);
    transpose_k<<<dim3(4096 / 32, 64 / 32, 32),  tb, 0, stream>>>(f0, T0, 64,  4096);
    transpose_k<<<dim3(1024 / 32, 128 / 32, 32), tb, 0, stream>>>(f1, T1, 128, 1024);
    transpose_k<<<dim3(256 / 32,  256 / 32, 32), tb, 0, stream>>>(f2, T2, 256, 256);
    transpose_k<<<dim3(64 / 32,   512 / 32, 32), tb, 0, stream>>>(f3, T3, 512, 64);

    proj_phase1<<<dim3(NPTS / 256), dim3(256), 0, stream>>>(points, proM, out_hc, out_wc, meta);

    int total4 = FEAT_ELEMS / 4;   // 31457280
    proj_phase2<<<dim3(total4 / 256), dim3(256), 0, stream>>>(
        (const v4f*)T0, (const v4f*)T1, (const v4f*)T2, (const v4f*)T3,
        meta, (v4f*)out);
}

// Round 4
// 98.350 us; speedup vs baseline: 1.9213x; 1.0514x over previous
//
#include <hip/hip_runtime.h>

// PointProjection: B=32, N=4096, pyramids s=(64,32,16,8), C=(64,128,256,512).
// Output (B,N,960) + hc (B,N,1) + wc (B,N,1).
//
// Reference degenerates: xi==x1 always, so w12=w21=w22=0 and w11 in {0,1}.
// Each point is either a full 960-ch gather of pixel (y1,x1) or all zeros.
//
// R4: fuse {4 transposes + phase1} into one kernel (block-range decode) and
// vectorize the transpose to float4 on both global sides (64x64 tiles).
// Phase2 (write-bound, NT float4 stores) unchanged.

#define BB 32
#define NN 4096
#define NPTS (BB * NN)              // 131072 points
#define FEAT_ELEMS (NPTS * 960)     // 125829120 f32 of pixel_feature

typedef float v4f __attribute__((ext_vector_type(4)));

// Block ranges inside the fused kernel:
//  scale0: [0,    2048)  b=blk/64,  tileP=blk%64,           C=64,  P=4096
//  scale1: [2048, 3072)  local/32=b, rem: tileP=rem/2, tileC=rem%2, C=128, P=1024
//  scale2: [3072, 3584)  local/16=b, rem: tileP=rem/4, tileC=rem%4, C=256, P=256
//  scale3: [3584, 3840)  local/8=b,  tileC=local%8, tileP=0, C=512, P=64
//  phase1: [3840, 4352)  512 blocks x 256 threads = 131072 points
#define FUSED_BLOCKS 4352

__device__ __forceinline__ void tile_transpose(const float* __restrict__ ib,
                                               float* __restrict__ ob,
                                               int C, int P, int c0, int p0,
                                               float (*t)[65])
{
    int tid = threadIdx.x;            // 256
    int l16 = tid & 15, grp = tid >> 4;   // grp 0..15
#pragma unroll
    for (int it = 0; it < 4; ++it) {
        int c = it * 16 + grp;        // 0..63 within tile
        float4 v = *(const float4*)(ib + (size_t)(c0 + c) * P + p0 + l16 * 4);
        t[l16 * 4 + 0][c] = v.x;
        t[l16 * 4 + 1][c] = v.y;
        t[l16 * 4 + 2][c] = v.z;
        t[l16 * 4 + 3][c] = v.w;
    }
    __syncthreads();
#pragma unroll
    for (int it = 0; it < 4; ++it) {
        int p = it * 16 + grp;
        float4 v;
        v.x = t[p][l16 * 4 + 0];
        v.y = t[p][l16 * 4 + 1];
        v.z = t[p][l16 * 4 + 2];
        v.w = t[p][l16 * 4 + 3];
        *(float4*)(ob + (size_t)(p0 + p) * C + c0 + l16 * 4) = v;
    }
}

__global__ void __launch_bounds__(256)
fused_prep(const float* __restrict__ f0, const float* __restrict__ f1,
           const float* __restrict__ f2, const float* __restrict__ f3,
           float* __restrict__ T0, float* __restrict__ T1,
           float* __restrict__ T2, float* __restrict__ T3,
           const float* __restrict__ points, const float* __restrict__ proM,
           float* __restrict__ out_hc, float* __restrict__ out_wc,
           int4* __restrict__ meta)
{
    __shared__ float t[64][65];
    int blk = blockIdx.x;

    if (blk < 2048) {                        // scale 0: C=64, P=4096
        int b = blk >> 6, tp = blk & 63;
        tile_transpose(f0 + (size_t)b * 64 * 4096, T0 + (size_t)b * 64 * 4096,
                       64, 4096, 0, tp * 64, t);
        return;
    }
    if (blk < 3072) {                        // scale 1: C=128, P=1024
        int local = blk - 2048;
        int b = local >> 5, rem = local & 31;
        tile_transpose(f1 + (size_t)b * 128 * 1024, T1 + (size_t)b * 128 * 1024,
                       128, 1024, (rem & 1) * 64, (rem >> 1) * 64, t);
        return;
    }
    if (blk < 3584) {                        // scale 2: C=256, P=256
        int local = blk - 3072;
        int b = local >> 4, rem = local & 15;
        tile_transpose(f2 + (size_t)b * 256 * 256, T2 + (size_t)b * 256 * 256,
                       256, 256, (rem & 3) * 64, (rem >> 2) * 64, t);
        return;
    }
    if (blk < 3840) {                        // scale 3: C=512, P=64
        int local = blk - 3584;
        int b = local >> 3, tc = local & 7;
        tile_transpose(f3 + (size_t)b * 512 * 64, T3 + (size_t)b * 512 * 64,
                       512, 64, tc * 64, 0, t);
        return;
    }

    // ---- phase 1: projection + meta ----
    int pt = (blk - 3840) * 256 + threadIdx.x;   // < 131072
    int b = pt >> 12;
    const float* p = points + (size_t)pt * 3;
    float px = p[0], py = p[1], pz = p[2];
    const float* M = proM + b * 12;
    float a0 = M[0] * px + M[1] * py + M[2]  * pz + M[3];
    float a1 = M[4] * px + M[5] * py + M[6]  * pz + M[7];
    float a2 = M[8] * px + M[9] * py + M[10] * pz + M[11];
    float wcv = fminf(fmaxf(a0 / a2, 0.0f), 127.0f);
    float hcv = fminf(fmaxf(a1 / a2, 0.0f), 127.0f);
    out_hc[pt] = hcv;
    out_wc[pt] = wcv;

    int res[4];
    const int sizes[4] = {64, 32, 16, 8};
#pragma unroll
    for (int k = 0; k < 4; ++k) {
        int s = sizes[k];
        float sc = (float)s * (1.0f / 128.0f);
        float x = wcv * sc;
        float y = hcv * sc;
        int x1 = (int)x;
        int y1 = (int)y;
        int x2 = min((int)ceilf(x), s - 1);
        int y2 = min((int)ceilf(y), s - 1);
        int w  = (x2 - x1) * (y2 - y1);           // 0 or 1
        res[k] = w ? (y1 * s + x1) : -1;
    }
    meta[pt] = make_int4(res[0], res[1], res[2], res[3]);
}

// ---------------- Phase 2: contiguous row gather, float4 per thread --------
__global__ void __launch_bounds__(256)
proj_phase2(const v4f* __restrict__ T0,   // (b, 4096, 64)
            const v4f* __restrict__ T1,   // (b, 1024, 128)
            const v4f* __restrict__ T2,   // (b, 256, 256)
            const v4f* __restrict__ T3,   // (b, 64, 512)
            const int4* __restrict__ meta,
            v4f* __restrict__ outf)
{
    int i = blockIdx.x * blockDim.x + threadIdx.x;   // < 31457280
    int pt = i / 240;                                // 240 float4 per point
    int r  = i - pt * 240;
    int b  = pt >> 12;
    int4 m = meta[pt];

    v4f v = (v4f)(0.f, 0.f, 0.f, 0.f);
    if (r < 16) {
        if (m.x >= 0) v = T0[((size_t)b * 4096 + m.x) * 16 + r];
    } else if (r < 48) {
        if (m.y >= 0) v = T1[((size_t)b * 1024 + m.y) * 32 + (r - 16)];
    } else if (r < 112) {
        if (m.z >= 0) v = T2[((size_t)b * 256 + m.z) * 64 + (r - 48)];
    } else {
        if (m.w >= 0) v = T3[((size_t)b * 64 + m.w) * 128 + (r - 112)];
    }
    __builtin_nontemporal_store(v, &outf[i]);
}

extern "C" void kernel_launch(void* const* d_in, const int* in_sizes, int n_in,
                              void* d_out, int out_size, void* d_ws, size_t ws_size,
                              hipStream_t stream)
{
    const float* f0     = (const float*)d_in[0];
    const float* f1     = (const float*)d_in[1];
    const float* f2     = (const float*)d_in[2];
    const float* f3     = (const float*)d_in[3];
    const float* points = (const float*)d_in[4];
    const float* proM   = (const float*)d_in[5];

    float* out      = (float*)d_out;
    float* out_hc   = out + (size_t)FEAT_ELEMS;
    float* out_wc   = out_hc + NPTS;

    // Workspace layout (floats): T0 | T1 | T2 | T3 | meta
    float* T0 = (float*)d_ws;                          // 32*4096*64  = 8388608
    float* T1 = T0 + (size_t)32 * 4096 * 64;           // 32*1024*128 = 4194304
    float* T2 = T1 + (size_t)32 * 1024 * 128;          // 32*256*256  = 2097152
    float* T3 = T2 + (size_t)32 * 256 * 256;           // 32*64*512   = 1048576
    int4*  meta = (int4*)(T3 + (size_t)32 * 64 * 512); // 2 MiB

    fused_prep<<<dim3(FUSED_BLOCKS), dim3(256), 0, stream>>>(
        f0, f1, f2, f3, T0, T1, T2, T3, points, proM, out_hc, out_wc, meta);

    int total4 = FEAT_ELEMS / 4;   // 31457280
    proj_phase2<<<dim3(total4 / 256), dim3(256), 0, stream>>>(
        (const v4f*)T0, (const v4f*)T1, (const v4f*)T2, (const v4f*)T3,
        meta, (v4f*)out);
}